// Round 7
// baseline (492.679 us; speedup 1.0000x reference)
//
#include <hip/hip_runtime.h>
#include <math.h>

#define NB 4
#define NF 64
#define NPIX 16384
#define DK 256
#define DV 512
#define QKSCALE 0.4204482f

typedef __attribute__((ext_vector_type(8))) short bf16x8;
typedef __attribute__((ext_vector_type(4))) float f32x4;
#define MFMA16(a, b, c) __builtin_amdgcn_mfma_f32_16x16x32_bf16(a, b, c, 0, 0, 0)

__device__ __forceinline__ short f2bf(float f) {
  unsigned u = __builtin_bit_cast(unsigned, f);
  unsigned r = (u + 0x7FFFu + ((u >> 16) & 1u)) >> 16;
  return (short)r;
}
__device__ __forceinline__ float bf2f(short s) {
  unsigned u = ((unsigned)(unsigned short)s) << 16;
  return __builtin_bit_cast(float, u);
}

// workspace offsets (float units)
#define OFF_XUPT   0L          // bf16 [4][128y][128x][128c]      4,194,304 f
#define OFF_XAT    4194304L    // bf16 [4][128y][128x][64c]       2,097,152 f
#define OFF_NZT    6291456L    // bf16 [2][4][16384n][64c]        4,194,304 f
#define OFF_NZB    10485760L   // bf16 [2][4][64c][16384n]        4,194,304 f
#define OFF_NBT    14680064L   // bf16 [2][4][16384n][64c]        4,194,304 f
#define OFF_GPART  18874368L   // bf16 [2][4][128ch][256][80]    10,485,760 f
#define OFF_WB1    29360128L   // bf16 [9][64][128]                  36,864 f
#define OFF_WB2    29396992L   // bf16 [9][64][64]                   18,432 f
#define OFF_STYLE  29415424L   // [4][64] fp32                          256
#define OFF_RGBS   29415680L   // [4][3][128][128] fp32             196,608
#define OFF_QWB    29612288L   // bf16 [2][256][64]                  16,384 f
#define OFF_KWB    29628672L   // bf16 [2][256][64]                  16,384 f
#define OFF_F1WB   29645056L   // bf16 [2][128][64]                   8,192 f
#define OFF_F2WB   29653248L   // bf16 [2][64][128]                   8,192 f
#define OFF_MTT    29661440L   // bf16 [2][4][64][256]               65,536 f
// total 29,726,976 floats = 118.9 MB

#define CDIV(a,b) (((a)+(b)-1)/(b))

// ---------------- prep: weight bf16 conversions + style (one launch) ---------------------
__global__ void cvt4style_kernel(const float* __restrict__ qw, const float* __restrict__ kw,
                                 const float* __restrict__ f1w, const float* __restrict__ f2w,
                                 short* __restrict__ qwb, short* __restrict__ kwb,
                                 short* __restrict__ f1wb, short* __restrict__ f2wb,
                                 const float* __restrict__ istyle, const float* __restrict__ sw,
                                 const float* __restrict__ sb, float* __restrict__ styleb) {
  if (blockIdx.x == 384) {
    int b = threadIdx.x >> 6;
    int c = threadIdx.x & 63;
    float a = 0.f;
    const float* ip = istyle + b * 512;
    const float* wp = sw + c * 512;
    for (int l = 0; l < 512; ++l) a += ip[l] * wp[l];
    styleb[b * 64 + c] = a + sb[c];
    return;
  }
  int i = blockIdx.x * 256 + threadIdx.x;   // 98304 total
  if (i < 32768) qwb[i] = f2bf(qw[i]);
  else if (i < 65536) kwb[i - 32768] = f2bf(kw[i - 32768]);
  else if (i < 81920) f1wb[i - 65536] = f2bf(f1w[i - 65536]);
  else f2wb[i - 81920] = f2bf(f2w[i - 81920]);
}

// ---------------- demod weight prep (both convs, one launch) -> bf16 wb[9][64][CI] -------
__global__ void wnorm2_kernel(const float* __restrict__ W1, const float* __restrict__ W2,
                              short* __restrict__ wb1, short* __restrict__ wb2) {
  int bid = blockIdx.x;
  const float* W = (bid < 64) ? W1 : W2;
  short* wb = (bid < 64) ? wb1 : wb2;
  int CI = (bid < 64) ? 128 : 64;
  int co = bid & 63;
  int n = CI * 9;
  __shared__ float red[256];
  float s = 0.f;
  for (int idx = threadIdx.x; idx < n; idx += 256) {
    float w2 = 2.0f * W[co * n + idx];
    s += w2 * w2;
  }
  red[threadIdx.x] = s;
  __syncthreads();
  for (int off = 128; off > 0; off >>= 1) {
    if (threadIdx.x < off) red[threadIdx.x] += red[threadIdx.x + off];
    __syncthreads();
  }
  float sc = rsqrtf(red[0] + 1e-8f);
  for (int idx = threadIdx.x; idx < n; idx += 256) {
    int ci = idx / 9, k = idx - ci * 9;
    wb[(k * 64 + co) * CI + ci] = f2bf(2.0f * W[co * n + idx] * sc);
  }
}

// ---------------- fused bilinear up2 + NCHW->NHWC bf16 (x path) --------------------------
__global__ __launch_bounds__(256) void up2t_kernel(const float* __restrict__ in,
                                                   short* __restrict__ outT) {
  __shared__ float row[64 * 132];   // [xin][c] y-interpolated row
  int b = blockIdx.y, y = blockIdx.x, tid = threadIdx.x;
  float iy = y * 0.5f - 0.25f;
  int y0 = (int)floorf(iy); float wy = iy - (float)y0;
  int ylo = y0 < 0 ? 0 : y0;
  int yhi = y0 + 1 > 63 ? 63 : y0 + 1;
  for (int it = 0; it < 32; ++it) {
    int idx = it * 256 + tid;
    int c = idx >> 6, xin = idx & 63;
    const float* bp = in + ((long)(b * 128 + c)) * 4096;
    float v0 = bp[ylo * 64 + xin];
    float v1 = bp[yhi * 64 + xin];
    row[xin * 132 + c] = (1.f - wy) * v0 + wy * v1;
  }
  __syncthreads();
  int x = tid >> 1, c0 = (tid & 1) * 64;
  float ix = x * 0.5f - 0.25f;
  int x0 = (int)floorf(ix); float wx = ix - (float)x0;
  int xlo = x0 < 0 ? 0 : x0;
  int xhi = x0 + 1 > 63 ? 63 : x0 + 1;
  long obase = (((long)(b * 128 + y)) * 128 + x) * 128 + c0;
#pragma unroll
  for (int i = 0; i < 8; ++i) {
    bf16x8 pack;
#pragma unroll
    for (int r = 0; r < 8; ++r) {
      int c = c0 + i * 8 + r;
      float v = (1.f - wx) * row[xlo * 132 + c] + wx * row[xhi * 132 + c];
      pack[r] = f2bf(v);
    }
    *(bf16x8*)(outT + obase + i * 8) = pack;
  }
}

// ---------------- nzt: noise fp32 NCHW -> bf16 NCHW (nzB) + bf16 NHWC (nzT) --------------
// grid (128 chunks, NB, 2)
__global__ __launch_bounds__(256) void nzt_kernel(const float* __restrict__ nz1,
                                                  const float* __restrict__ nz2,
                                                  short* __restrict__ nzB,
                                                  short* __restrict__ nzT) {
  __shared__ __attribute__((aligned(16))) short Xl[128 * 72];
  int iz = blockIdx.z, b = blockIdx.y, ch = blockIdx.x;
  const float* nz = iz ? nz2 : nz1;
  int tid = threadIdx.x;
  int n0 = ch * 128;
  for (int k = 0; k < 32; ++k) {
    int idx = tid + k * 256;
    int c = idx >> 7, n = idx & 127;
    short bv = f2bf(nz[((long)b * 64 + c) * NPIX + n0 + n]);
    nzB[((long)(iz * NB + b) * 64 + c) * NPIX + n0 + n] = bv;
    Xl[n * 72 + c] = bv;
  }
  __syncthreads();
  int n = tid >> 1, c0 = (tid & 1) * 32;
  long ob2 = ((long)(iz * NB + b) * NPIX + n0 + n) * 64 + c0;
#pragma unroll
  for (int i = 0; i < 4; ++i)
    *(bf16x8*)(nzT + ob2 + i * 8) = *(const bf16x8*)(Xl + n * 72 + c0 + i * 8);
}

// ---------------- pk: Gpart(bf16)[iz][b][ch][256d][80] ; col64 = row-sum of P ------------
// grid (128 ch, NB, 2), block 256. No staging: GEMM1 A from nzT, GEMM2 B from nzB.
__global__ __launch_bounds__(256, 4) void pk_kernel(const short* __restrict__ nzT,
                                                    const short* __restrict__ nzB,
                                                    const short* __restrict__ kwb,
                                                    short* __restrict__ Gpartb) {
  __shared__ __attribute__((aligned(16))) char lds[18432];
  short* Ph = (short*)lds;                 // [64d][136n]
  float* sbuf = (float*)(lds + 17408);     // [4w][64d]
  int iz = blockIdx.z, b = blockIdx.y, ch = blockIdx.x;
  int tid = threadIdx.x;
  int w = tid >> 6, lane = tid & 63, quad = lane >> 4, l15 = lane & 15;
  int n0 = ch * 128;
  const short* xT = nzT + ((long)(iz * NB + b) * NPIX + n0) * 64;
  const short* xB = nzB + ((long)(iz * NB + b) * 64) * NPIX + n0;
  const short* kwp = kwb + iz * DK * NF;
  short* gp = Gpartb + (((long)(iz * NB + b) * 128 + ch) * 256) * 80;
  for (int q = 0; q < 4; ++q) {
    // GEMM1 (swapped): C[pixel][d] = X^T @ kw^T for this q's 64 d
    f32x4 acc[2][4];
#pragma unroll
    for (int j = 0; j < 2; ++j)
#pragma unroll
      for (int dt = 0; dt < 4; ++dt) acc[j][dt] = (f32x4){0.f, 0.f, 0.f, 0.f};
#pragma unroll
    for (int j = 0; j < 2; ++j) {
      int ntile = 2 * w + j;
#pragma unroll
      for (int ks = 0; ks < 2; ++ks) {
        bf16x8 afr = *(const bf16x8*)(xT + (ntile * 16 + l15) * 64 + ks * 32 + quad * 8);
#pragma unroll
        for (int dt = 0; dt < 4; ++dt) {
          bf16x8 bfr = *(const bf16x8*)(kwp + ((q * 64 + dt * 16 + l15) * 64 + ks * 32 + quad * 8));
          acc[j][dt] = MFMA16(afr, bfr, acc[j][dt]);
        }
      }
    }
    // exp -> Ph [d][n] (vectorized), row-sums -> sbuf
    float ssum[4] = {0.f, 0.f, 0.f, 0.f};
#pragma unroll
    for (int j = 0; j < 2; ++j)
#pragma unroll
      for (int dt = 0; dt < 4; ++dt) {
        short4 pv;
        float ps = 0.f;
#pragma unroll
        for (int r = 0; r < 4; ++r) {
          float p = __expf(acc[j][dt][r] * QKSCALE);
          ps += p;
          ((short*)&pv)[r] = f2bf(p);
        }
        *(short4*)(Ph + (dt * 16 + l15) * 136 + (2 * w + j) * 16 + quad * 4) = pv;
        ssum[dt] += ps;
      }
#pragma unroll
    for (int dt = 0; dt < 4; ++dt) {
      ssum[dt] += __shfl_xor(ssum[dt], 16);
      ssum[dt] += __shfl_xor(ssum[dt], 32);
    }
    if (quad == 0) {
#pragma unroll
      for (int dt = 0; dt < 4; ++dt) sbuf[w * 64 + dt * 16 + l15] = ssum[dt];
    }
    __syncthreads();
    // GEMM2: G[d][c] = Ph @ X^T ; wave w -> d-tile w
#pragma unroll
    for (int ct = 0; ct < 4; ++ct) {
      f32x4 g = (f32x4){0.f, 0.f, 0.f, 0.f};
#pragma unroll
      for (int ks = 0; ks < 4; ++ks) {
        bf16x8 afr = *(const bf16x8*)(Ph + (w * 16 + l15) * 136 + ks * 32 + quad * 8);
        bf16x8 bfr = *(const bf16x8*)(xB + (ct * 16 + l15) * NPIX + ks * 32 + quad * 8);
        g = MFMA16(afr, bfr, g);
      }
#pragma unroll
      for (int r = 0; r < 4; ++r)
        gp[(q * 64 + w * 16 + quad * 4 + r) * 80 + ct * 16 + l15] = f2bf(g[r]);
    }
    // col 64: denominator
    if (l15 == 0) {
#pragma unroll
      for (int r = 0; r < 4; ++r) {
        int dl = w * 16 + quad * 4 + r;
        float sv = sbuf[dl] + sbuf[64 + dl] + sbuf[128 + dl] + sbuf[192 + dl];
        gp[(q * 64 + dl) * 80 + 64] = f2bf(sv);
      }
    }
    __syncthreads();
  }
}

// ---------------- ctxM: merge Gpart(bf16) -> ctx -> MtT (bf16 [iz][b][64c][256d]) --------
__global__ void ctxM_kernel(const short* __restrict__ Gpartb, const float* __restrict__ vw,
                            const float* __restrict__ ow, short* __restrict__ MtTb) {
  int iz = blockIdx.z, b = blockIdx.y, dt = blockIdx.x * 16;
  int h = dt >> 5;
  __shared__ float Gs[16][81];
  __shared__ float ctxs[16][68];
  int t = threadIdx.x;
  const short* gbase = Gpartb + ((long)(iz * NB + b) * 128) * 256 * 80;
  const float* vwp = vw + iz * DV * NF;
  const float* owp = ow + iz * NF * DV;
  for (int idx = t; idx < 1280; idx += 256) {
    int dl = idx / 80, c = idx - dl * 80;
    float s = 0.f;
    const short* gp = gbase + (long)(dt + dl) * 80 + c;
    for (int ch = 0; ch < 128; ++ch) s += bf2f(gp[(long)ch * 20480]);
    Gs[dl][c] = s;
  }
  __syncthreads();
  for (int idx = t; idx < 1024; idx += 256) {
    int dl = idx & 15, e = idx >> 4;
    const float* vp = vwp + (h * 64 + e) * 64;
    float a = 0.f;
#pragma unroll
    for (int c = 0; c < 64; ++c) a += Gs[dl][c] * vp[c];
    ctxs[dl][e] = a / Gs[dl][64];
  }
  __syncthreads();
  for (int idx = t; idx < 1024; idx += 256) {
    int dl = idx & 15, c = idx >> 4;
    const float* op = owp + c * 512 + h * 64;
    float a = 0.f;
#pragma unroll
    for (int e = 0; e < 64; ++e) a += op[e] * ctxs[dl][e];
    MtTb[((long)(iz * NB + b) * 64 + c) * 256 + dt + dl] = f2bf(a);
  }
}

// ---------------- attnd4: per-head fused attn+FF from nzT, NHWC bf16 out -----------------
// grid (256, NB, 2), block 256 = 4 waves, 16 px/wave. Per-wave LDS 4 KB.
__global__ __launch_bounds__(256, 8) void attnd4_kernel(
    const short* __restrict__ nzT, const short* __restrict__ qwb,
    const short* __restrict__ MtTb, const float* __restrict__ ob,
    const float* __restrict__ gap, const short* __restrict__ f1wb,
    const float* __restrict__ f1b, const short* __restrict__ f2wb,
    const float* __restrict__ f2b, const float* __restrict__ gfp,
    short* __restrict__ noutT) {
  __shared__ __attribute__((aligned(16))) short lds[4 * 2048];
  int iz = blockIdx.z, b = blockIdx.y;
  int tid = threadIdx.x;
  int w = tid >> 6, lane = tid & 63, quad = lane >> 4, l15 = lane & 15;
  int n0 = blockIdx.x * 64 + w * 16;
  short* Ys = lds + w * 2048;     // [16][72] (Y then H chunks)
  short* Es = Ys + 1152;          // [16][56]
  const short* qwp = qwb + iz * DK * NF;
  const short* f1wp = f1wb + iz * 128 * 64;
  const short* f2wp = f2wb + iz * 64 * 128;
  const float* obp = ob + iz * NF;
  const float* f1bp = f1b + iz * 128;
  const float* f2bp = f2b + iz * NF;
  float ga = gap[iz], gf = gfp[iz];
  const short* xrow = nzT + ((long)(iz * NB + b) * NPIX + n0) * 64;
  bf16x8 xfr0 = *(const bf16x8*)(xrow + l15 * 64 + quad * 8);
  bf16x8 xfr1 = *(const bf16x8*)(xrow + l15 * 64 + 32 + quad * 8);
  const short* mtb = MtTb + (long)(iz * NB + b) * 64 * 256;
  f32x4 acc2[4];
#pragma unroll
  for (int ct = 0; ct < 4; ++ct) acc2[ct] = (f32x4){0.f, 0.f, 0.f, 0.f};
  // per-head: GEMM1 (q) -> softmax -> E-strip -> GEMM2 chunk
#pragma unroll
  for (int h = 0; h < 8; ++h) {
    f32x4 q[2];
#pragma unroll
    for (int dd = 0; dd < 2; ++dd) {
      q[dd] = (f32x4){0.f, 0.f, 0.f, 0.f};
      bf16x8 a0 = *(const bf16x8*)(qwp + (((2 * h + dd) * 16 + l15) * 64 + quad * 8));
      q[dd] = MFMA16(a0, xfr0, q[dd]);
      bf16x8 a1 = *(const bf16x8*)(qwp + (((2 * h + dd) * 16 + l15) * 64 + 32 + quad * 8));
      q[dd] = MFMA16(a1, xfr1, q[dd]);
    }
    float part = 0.f;
#pragma unroll
    for (int dd = 0; dd < 2; ++dd)
#pragma unroll
      for (int r = 0; r < 4; ++r) {
        float e = __expf(q[dd][r] * QKSCALE);
        q[dd][r] = e;
        part += e;
      }
    float p2 = part + __shfl_xor(part, 16);
    float s = p2 + __shfl_xor(p2, 32);
    float inv = 1.0f / s;
#pragma unroll
    for (int dd = 0; dd < 2; ++dd) {
      short4 ev;
      ev.x = f2bf(q[dd][0] * inv); ev.y = f2bf(q[dd][1] * inv);
      ev.z = f2bf(q[dd][2] * inv); ev.w = f2bf(q[dd][3] * inv);
      *(short4*)(Es + l15 * 56 + dd * 16 + quad * 4) = ev;
    }
    bf16x8 efr = *(const bf16x8*)(Es + l15 * 56 + quad * 8);
#pragma unroll
    for (int ct = 0; ct < 4; ++ct) {
      bf16x8 afr = *(const bf16x8*)(mtb + ((ct * 16 + l15) * 256 + h * 32 + quad * 8));
      acc2[ct] = MFMA16(afr, efr, acc2[ct]);
    }
  }
  // residual y = x + ga*(o + ob); x from nzT; y -> Ys (bf16) + fp32 regs
  float yreg[4][4];
#pragma unroll
  for (int ct = 0; ct < 4; ++ct) {
    int c0 = ct * 16 + quad * 4;
    short4 xs = *(const short4*)(xrow + l15 * 64 + c0);
    float xv[4] = {bf2f(xs.x), bf2f(xs.y), bf2f(xs.z), bf2f(xs.w)};
    short4 ys;
#pragma unroll
    for (int r = 0; r < 4; ++r) yreg[ct][r] = xv[r] + ga * (acc2[ct][r] + obp[c0 + r]);
    ys.x = f2bf(yreg[ct][0]); ys.y = f2bf(yreg[ct][1]);
    ys.z = f2bf(yreg[ct][2]); ys.w = f2bf(yreg[ct][3]);
    *(short4*)(Ys + l15 * 72 + c0) = ys;
  }
  bf16x8 yfr0 = *(const bf16x8*)(Ys + l15 * 72 + quad * 8);
  bf16x8 yfr1 = *(const bf16x8*)(Ys + l15 * 72 + 32 + quad * 8);
  // GEMM3: h1[128j x 16n]
  f32x4 acc3[8];
#pragma unroll
  for (int jt = 0; jt < 8; ++jt) {
    acc3[jt] = (f32x4){0.f, 0.f, 0.f, 0.f};
    bf16x8 a0 = *(const bf16x8*)(f1wp + ((jt * 16 + l15) * 64 + quad * 8));
    acc3[jt] = MFMA16(a0, yfr0, acc3[jt]);
    bf16x8 a1 = *(const bf16x8*)(f1wp + ((jt * 16 + l15) * 64 + 32 + quad * 8));
    acc3[jt] = MFMA16(a1, yfr1, acc3[jt]);
  }
  // GEMM4 in 2 chunks of 64 j through the Ys strip
  f32x4 acc4[4];
#pragma unroll
  for (int ct = 0; ct < 4; ++ct) acc4[ct] = (f32x4){0.f, 0.f, 0.f, 0.f};
#pragma unroll
  for (int p = 0; p < 2; ++p) {
#pragma unroll
    for (int jj = 0; jj < 4; ++jj) {
      int jt = p * 4 + jj;
      short4 hs;
#pragma unroll
      for (int r = 0; r < 4; ++r) {
        float a = acc3[jt][r] + f1bp[jt * 16 + quad * 4 + r];
        a = a > 0.f ? a : 0.2f * a;
        ((short*)&hs)[r] = f2bf(a);
      }
      *(short4*)(Ys + l15 * 72 + jj * 16 + quad * 4) = hs;
    }
    bf16x8 h0 = *(const bf16x8*)(Ys + l15 * 72 + quad * 8);
    bf16x8 h1 = *(const bf16x8*)(Ys + l15 * 72 + 32 + quad * 8);
#pragma unroll
    for (int ct = 0; ct < 4; ++ct) {
      bf16x8 a0 = *(const bf16x8*)(f2wp + ((ct * 16 + l15) * 128 + p * 64 + quad * 8));
      acc4[ct] = MFMA16(a0, h0, acc4[ct]);
      bf16x8 a1 = *(const bf16x8*)(f2wp + ((ct * 16 + l15) * 128 + p * 64 + 32 + quad * 8));
      acc4[ct] = MFMA16(a1, h1, acc4[ct]);
    }
  }
  // output NHWC bf16
#pragma unroll
  for (int ct = 0; ct < 4; ++ct) {
    int c0 = ct * 16 + quad * 4;
    short4 ov;
#pragma unroll
    for (int r = 0; r < 4; ++r)
      ((short*)&ov)[r] = f2bf(yreg[ct][r] + gf * (acc4[ct][r] + f2bp[c0 + r]));
    *(short4*)(noutT + ((long)(iz * NB + b) * NPIX + n0 + l15) * 64 + c0) = ov;
  }
}

// ---------------- MFMA 3x3 conv, x-split (64 px/block): NHWC bf16 in/addend --------------
// grid (2 bx, 128 y, NB). wave w -> 16 px, all 4 co-tiles.
__global__ __launch_bounds__(256, 4) void convmfma_kernel(
    const short* __restrict__ inT, int CI, const short* __restrict__ wb,
    const short* __restrict__ addnT, float* __restrict__ out_nchw,
    short* __restrict__ out_nhwc, const float* __restrict__ rgbw,
    const float* __restrict__ styleb, const float* __restrict__ prev,
    float* __restrict__ rgbs) {
  __shared__ __attribute__((aligned(16))) short Bs[3 * 66 * 40];  // [r][xi][ci32 pad40]
  int b = blockIdx.z, y = blockIdx.y, x0 = blockIdx.x * 64;
  int tid = threadIdx.x;
  int w = tid >> 6, lane = tid & 63, quad = lane >> 4, l15 = lane & 15;
  int KS = CI >> 5;
  f32x4 acc[4];
#pragma unroll
  for (int ct = 0; ct < 4; ++ct) acc[ct] = (f32x4){0.f, 0.f, 0.f, 0.f};
  for (int ks = 0; ks < KS; ++ks) {
    if (ks) __syncthreads();
    for (int t = tid; t < 792; t += 256) {
      int ci8 = t & 3, xr = t >> 2;
      int xi = xr % 66, r = xr / 66;
      int gy = y + r - 1, gx = x0 - 1 + xi;
      bf16x8 v = {0, 0, 0, 0, 0, 0, 0, 0};
      if (gy >= 0 && gy < 128 && gx >= 0 && gx < 128)
        v = *(const bf16x8*)(inT + (((long)(b * 128 + gy)) * 128 + gx) * CI + ks * 32 + ci8 * 8);
      *(bf16x8*)(Bs + (r * 66 + xi) * 40 + ci8 * 8) = v;
    }
    __syncthreads();
#pragma unroll
    for (int sh = 0; sh < 9; ++sh) {
      int dyv = sh / 3, dxv = sh - dyv * 3;
      const short* wrow = wb + (sh * 64 + l15) * CI + ks * 32 + quad * 8;
      bf16x8 a0 = *(const bf16x8*)(wrow);
      bf16x8 a1 = *(const bf16x8*)(wrow + 16 * CI);
      bf16x8 a2 = *(const bf16x8*)(wrow + 32 * CI);
      bf16x8 a3 = *(const bf16x8*)(wrow + 48 * CI);
      int xi = w * 16 + l15 + dxv;
      bf16x8 bf = *(const bf16x8*)(Bs + (dyv * 66 + xi) * 40 + quad * 8);
      acc[0] = MFMA16(a0, bf, acc[0]);
      acc[1] = MFMA16(a1, bf, acc[1]);
      acc[2] = MFMA16(a2, bf, acc[2]);
      acc[3] = MFMA16(a3, bf, acc[3]);
    }
  }
  // epilogue: lrelu(conv + addn(bf16 NHWC)), stores, optional rgb
  int x = x0 + w * 16 + l15;
  long nidx = ((long)(b * 128 + y)) * 128 + x;
  float p0 = 0.f, p1 = 0.f, p2 = 0.f;
#pragma unroll
  for (int ct = 0; ct < 4; ++ct) {
    short4 ad = *(const short4*)(addnT + nidx * 64 + ct * 16 + quad * 4);
    float av[4] = {bf2f(ad.x), bf2f(ad.y), bf2f(ad.z), bf2f(ad.w)};
    float v[4];
#pragma unroll
    for (int r = 0; r < 4; ++r) {
      float a = acc[ct][r] + av[r];
      v[r] = a > 0.f ? a : 0.2f * a;
    }
    if (out_nchw) {
#pragma unroll
      for (int r = 0; r < 4; ++r) {
        int co = ct * 16 + quad * 4 + r;
        out_nchw[((long)(b * 64 + co)) * 16384 + y * 128 + x] = v[r];
      }
    }
    if (out_nhwc) {
      short4 pv;
      pv.x = f2bf(v[0]); pv.y = f2bf(v[1]); pv.z = f2bf(v[2]); pv.w = f2bf(v[3]);
      *(short4*)(out_nhwc + nidx * 64 + ct * 16 + quad * 4) = pv;
    }
    if (rgbw) {
#pragma unroll
      for (int r = 0; r < 4; ++r) {
        int co = ct * 16 + quad * 4 + r;
        float mv = (styleb[b * 64 + co] + 1.0f) * v[r];
        p0 += rgbw[co] * mv;
        p1 += rgbw[64 + co] * mv;
        p2 += rgbw[128 + co] * mv;
      }
    }
  }
  if (rgbw) {
    p0 += __shfl_xor(p0, 16); p0 += __shfl_xor(p0, 32);
    p1 += __shfl_xor(p1, 16); p1 += __shfl_xor(p1, 32);
    p2 += __shfl_xor(p2, 16); p2 += __shfl_xor(p2, 32);
    if (quad == 0) {
      long pi = y * 128 + x;
      rgbs[((long)(b * 3 + 0)) * 16384 + pi] = p0 + prev[((long)(b * 3 + 0)) * 16384 + pi];
      rgbs[((long)(b * 3 + 1)) * 16384 + pi] = p1 + prev[((long)(b * 3 + 1)) * 16384 + pi];
      rgbs[((long)(b * 3 + 2)) * 16384 + pi] = p2 + prev[((long)(b * 3 + 2)) * 16384 + pi];
    }
  }
}

// ---------------- fused bilinear up2 + [1,2,1] blur (rgb tail) ---------------------------
__global__ void upblur_kernel(const float* __restrict__ rgbs, float* __restrict__ out) {
  __shared__ float rows[3][128];
  int bc = blockIdx.y, Y = blockIdx.x, X = threadIdx.x;
  int m = Y >> 1;
  const float* base = rgbs + (long)bc * 16384;
  for (int t = X; t < 384; t += 256) {
    int sr = t >> 7, xx = t & 127;
    int rr = m - 1 + sr;
    rr = rr < 0 ? 0 : (rr > 127 ? 127 : rr);
    rows[sr][xx] = base[rr * 128 + xx];
  }
  __syncthreads();
  const float w3[3] = {1.f, 2.f, 1.f};
  float s = 0.f;
#pragma unroll
  for (int dy = -1; dy <= 1; ++dy) {
    int Yv = Y + dy;
    if (Yv < 0 || Yv > 255) continue;
    float iy = Yv * 0.5f - 0.25f;
    int y0 = (int)floorf(iy); float wy = iy - (float)y0;
    int ylo = y0 < 0 ? 0 : y0;
    int yhi = y0 + 1 > 127 ? 127 : y0 + 1;
    int slo = ylo - m + 1, shi = yhi - m + 1;
#pragma unroll
    for (int dx = -1; dx <= 1; ++dx) {
      int Xv = X + dx;
      if (Xv < 0 || Xv > 255) continue;
      float ix = Xv * 0.5f - 0.25f;
      int x0 = (int)floorf(ix); float wx = ix - (float)x0;
      int xlo = x0 < 0 ? 0 : x0;
      int xhi = x0 + 1 > 127 ? 127 : x0 + 1;
      float v = (1.f - wy) * ((1.f - wx) * rows[slo][xlo] + wx * rows[slo][xhi])
              + wy * ((1.f - wx) * rows[shi][xlo] + wx * rows[shi][xhi]);
      s += w3[dy + 1] * w3[dx + 1] * v;
    }
  }
  out[(long)bc * 65536 + Y * 256 + X] = s * (1.0f / 16.0f);
}

extern "C" void kernel_launch(void* const* d_in, const int* in_sizes, int n_in,
                              void* d_out, int out_size, void* d_ws, size_t ws_size,
                              hipStream_t stream) {
  (void)in_sizes; (void)n_in; (void)out_size; (void)ws_size;
  const float* x        = (const float*)d_in[0];
  const float* prev_rgb = (const float*)d_in[1];
  const float* istyle   = (const float*)d_in[2];
  const float* noise1   = (const float*)d_in[3];
  const float* noise2   = (const float*)d_in[4];
  const float* conv1_w  = (const float*)d_in[5];
  const float* conv2_w  = (const float*)d_in[6];
  const float* style_w  = (const float*)d_in[7];
  const float* style_b  = (const float*)d_in[8];
  const float* rgb_w    = (const float*)d_in[9];
  const float* qw       = (const float*)d_in[10];
  const float* kw       = (const float*)d_in[11];
  const float* vw       = (const float*)d_in[12];
  const float* ow       = (const float*)d_in[13];
  const float* ob       = (const float*)d_in[14];
  const float* ga       = (const float*)d_in[15];
  const float* f1w      = (const float*)d_in[16];
  const float* f1b      = (const float*)d_in[17];
  const float* f2w      = (const float*)d_in[18];
  const float* f2b      = (const float*)d_in[19];
  const float* gf       = (const float*)d_in[20];
  float* out_x   = (float*)d_out;
  float* out_rgb = out_x + 4194304;
  float* ws = (float*)d_ws;

  short* xupT   = (short*)(ws + OFF_XUPT);
  short* xaT    = (short*)(ws + OFF_XAT);
  short* nzT    = (short*)(ws + OFF_NZT);
  short* nzB    = (short*)(ws + OFF_NZB);
  short* nbufT  = (short*)(ws + OFF_NBT);
  short* Gpartb = (short*)(ws + OFF_GPART);
  short* wb1    = (short*)(ws + OFF_WB1);
  short* wb2    = (short*)(ws + OFF_WB2);
  float* styleb = ws + OFF_STYLE;
  float* rgbs   = ws + OFF_RGBS;
  short* qwb    = (short*)(ws + OFF_QWB);
  short* kwb    = (short*)(ws + OFF_KWB);
  short* f1wb   = (short*)(ws + OFF_F1WB);
  short* f2wb   = (short*)(ws + OFF_F2WB);
  short* MtTb   = (short*)(ws + OFF_MTT);

  // prep (independent)
  cvt4style_kernel<<<385, 256, 0, stream>>>(qw, kw, f1w, f2w, qwb, kwb, f1wb, f2wb,
                                            istyle, style_w, style_b, styleb);
  wnorm2_kernel<<<128, 256, 0, stream>>>(conv1_w, conv2_w, wb1, wb2);
  up2t_kernel<<<dim3(128, NB), 256, 0, stream>>>(x, xupT);
  nzt_kernel<<<dim3(128, NB, 2), 256, 0, stream>>>(noise1, noise2, nzB, nzT);

  // attention stacks (both i merged per launch)
  pk_kernel<<<dim3(128, NB, 2), 256, 0, stream>>>(nzT, nzB, kwb, Gpartb);
  ctxM_kernel<<<dim3(16, NB, 2), 256, 0, stream>>>(Gpartb, vw, ow, MtTb);
  attnd4_kernel<<<dim3(256, NB, 2), 256, 0, stream>>>(nzT, qwb, MtTb, ob, ga,
                                                      f1wb, f1b, f2wb, f2b, gf, nbufT);

  // convs
  convmfma_kernel<<<dim3(2, 128, NB), 256, 0, stream>>>(
      xupT, 128, wb1, nbufT, nullptr, xaT, nullptr, nullptr, nullptr, nullptr);
  convmfma_kernel<<<dim3(2, 128, NB), 256, 0, stream>>>(
      xaT, 64, wb2, nbufT + 4194304L, out_x, nullptr, rgb_w, styleb, prev_rgb, rgbs);

  upblur_kernel<<<dim3(256, 12), 256, 0, stream>>>(rgbs, out_rgb);
}